// Round 5
// baseline (135.769 us; speedup 1.0000x reference)
//
#include <hip/hip_runtime.h>
#include <math.h>

#define TL 2048
#define PI_D 3.14159265358979323846

typedef __attribute__((ext_vector_type(8))) short short8v;
typedef __attribute__((ext_vector_type(4))) float float4v;

__device__ __forceinline__ unsigned short bf16_rne(float f) {
  unsigned u = __float_as_uint(f);
  return (unsigned short)((u + 0x7FFFu + ((u >> 16) & 1u)) >> 16);
}

// ---------------------------------------------------------------------------
// Build shift kernels. 80 blocks: every block b builds bf16 shift-replica
// G-layout rows BFrep[b][s][z], z in [0,4104), G[z] = k[4095 - z + s]
// (zero outside tap range). b in [64,80) additionally writes kerC = exclusive
// prefix of taps (for the shifted step-mask identity).
// k[d] = -(sin(2*pi*r)/N)*(-1)^d * cot(pi*d/N - beta), N=6144,
// beta=pi*s/3073, r=frac(3072 s/3073), s=shift*2048/3; d->0 limit = 1.
// ---------------------------------------------------------------------------
__global__ __launch_bounds__(256) void build_kernels_k(const float* __restrict__ shifts,
                                                       float* __restrict__ kerC,
                                                       unsigned short* __restrict__ BFrep) {
  __shared__ float kf[4104];
  __shared__ float wsum[4];
  int b = blockIdx.x;
  int tid = threadIdx.x;
  double s;
  if (b < 64) s = (double)b * (1.0 / 63.0) * (2048.0 / 3.0);
  else        s = (double)shifts[b - 64] * (2048.0 / 3.0);
  double beta = PI_D * s / 3073.0;
  double y = 3072.0 * s / 3073.0;
  double r = y - rint(y);
  double wv = -sin(2.0 * PI_D * r) / 6144.0;
  for (int idx = tid; idx < 4104; idx += 256) {
    float val = 0.0f;
    if (idx < 4095) {
      int d = idx - 2047;
      double x = PI_D * (double)d / 6144.0 - beta;
      if (fabs(x) < 1e-9) {
        val = 1.0f;
      } else {
        double c = wv * (cos(x) / sin(x));
        if (d & 1) c = -c;
        val = (float)c;
      }
    }
    kf[idx] = val;
  }
  __syncthreads();
  // bf16 replicas for all 80 kernels
  for (int c = tid; c < 4096; c += 256) {
    int sr = c >> 9;
    int m = c & 511;
    int A = 4095 - 8 * m + sr;
    unsigned short out[8];
#pragma unroll
    for (int rr = 0; rr < 8; ++rr) out[rr] = bf16_rne(kf[A - rr]);
    *(short8v*)(BFrep + ((size_t)(b * 8 + sr)) * 4104 + 8 * m) = *(short8v*)out;
  }
  if (b >= 64) {
    // exclusive prefix of kf[0..4095] -> kerC
    float s0 = 0.f;
    int base = tid * 16;
#pragma unroll
    for (int i = 0; i < 16; ++i) s0 += kf[base + i];
    int lane = tid & 63;
    float v = s0;
#pragma unroll
    for (int d = 1; d < 64; d <<= 1) {
      float o = __shfl_up(v, (unsigned)d, 64);
      if (lane >= d) v += o;
    }
    if (lane == 63) wsum[tid >> 6] = v;
    __syncthreads();
    float woff = 0.f;
    for (int k = 0; k < (tid >> 6); ++k) woff += wsum[k];
    float run = v + woff - s0;
    float* crow = kerC + (b - 64) * 4096;
#pragma unroll
    for (int i = 0; i < 16; ++i) {
      crow[base + i] = run;
      run += kf[base + i];
    }
  }
}

// ---------------------------------------------------------------------------
// tsh via skewed-A MFMA: tsh[p][128r + c] = sum_k time[p][128r+k]*K_p[2047+c-k]
// A[r][k] = time[128r+k] (zero-padded, k in [-1920,2048), 124 chunks of 32),
// staged in LDS with XOR swizzle, exact hi/lo bf16 split. B[k][col] =
// K[2047+c0+col-k], read from BFrep rows (64+p) straight from global (L2-hot)
// with register prefetch. Grid: 16 blocks (one per p), 4 waves, wave w covers
// cols c0 = 32w + 16ct, ct in {0,1}.
// ---------------------------------------------------------------------------
__global__ __launch_bounds__(256) void tsh_mfma_k(const float* __restrict__ time_in,
                                                  const unsigned short* __restrict__ BFrep,
                                                  unsigned short* __restrict__ tsh_b) {
  __shared__ __align__(16) unsigned char smem[23552];  // 2 planes x 5888 u16
  int p = blockIdx.x;
  int tid = threadIdx.x;
  int l = tid & 63, w = tid >> 6;
  int p16 = l & 15, g = l >> 4;
  int hb = p16 >> 3, srep = p16 & 7;

  // zero-fill both planes
  short8v zz = {0, 0, 0, 0, 0, 0, 0, 0};
  for (int i = tid; i < 1472; i += 256) *(short8v*)(smem + i * 16) = zz;
  __syncthreads();
  // stage time hi/lo (swizzled): thread stages elems [8*tid, 8*tid+8)
  {
    float4v t0 = *(const float4v*)(time_in + p * 2048 + tid * 8);
    float4v t1 = *(const float4v*)(time_in + p * 2048 + tid * 8 + 4);
    short8v hv, lv;
#pragma unroll
    for (int i = 0; i < 8; ++i) {
      float f = (i < 4) ? t0[i] : t1[i - 4];
      unsigned short h = bf16_rne(f);
      float hf = __uint_as_float(((unsigned)h) << 16);
      hv[i] = (short)h;
      lv[i] = (short)bf16_rne(f - hf);
    }
    int be = 3840 + 16 * tid;
    int ad = be ^ ((((unsigned)be >> 8) & 7) << 4);
    *(short8v*)(smem + ad) = hv;
    *(short8v*)(smem + 11776 + ad) = lv;
  }
  __syncthreads();

  // B global base (per ct): z0 = 128 - 8hb - c0 + 32q + 8g
  const unsigned short* brow = BFrep + ((size_t)(64 + p) * 8 + srep) * 4104;
  const unsigned short* bp0 = brow + 128 - 8 * hb - (32 * w + 0) + 8 * g;
  const unsigned short* bp1 = bp0 - 16;

  float4v acc0 = {0.f, 0.f, 0.f, 0.f};
  float4v acc1 = {0.f, 0.f, 0.f, 0.f};
  short8v B0 = *(const short8v*)(bp0);
  short8v B1 = *(const short8v*)(bp1);
#pragma unroll 4
  for (int q = 0; q < 124; ++q) {
    short8v C0 = B0, C1 = B1;
    if (q < 123) {
      B0 = *(const short8v*)(bp0 + 32 * (q + 1));
      B1 = *(const short8v*)(bp1 + 32 * (q + 1));
    }
    int bb = (p16 << 8) + (q << 6) + (g << 4);
    int ad = bb ^ ((((unsigned)bb >> 8) & 7) << 4);
    short8v ah = *(const short8v*)(smem + ad);
    short8v al = *(const short8v*)(smem + 11776 + ad);
    acc0 = __builtin_amdgcn_mfma_f32_16x16x32_bf16(ah, C0, acc0, 0, 0, 0);
    acc1 = __builtin_amdgcn_mfma_f32_16x16x32_bf16(ah, C1, acc1, 0, 0, 0);
    acc0 = __builtin_amdgcn_mfma_f32_16x16x32_bf16(al, C0, acc0, 0, 0, 0);
    acc1 = __builtin_amdgcn_mfma_f32_16x16x32_bf16(al, C1, acc1, 0, 0, 0);
  }
  // C: row = 4g + rr, col = p16; t = 128*row + 32w + 16ct + col
#pragma unroll
  for (int rr = 0; rr < 4; ++rr) {
    int row = 4 * g + rr;
    tsh_b[p * 2048 + 128 * row + 32 * w + p16] = bf16_rne(acc0[rr]);
    tsh_b[p * 2048 + 128 * row + 32 * w + 16 + p16] = bf16_rne(acc1[rr]);
  }
}

// ---------------------------------------------------------------------------
// Mega kernel:
//  bx in [0,256): expT sliding-ring MFMA. j = bx>>2, t-base = (bx&3)*512.
//    Wave w owns 8 t-tiles (128 t) with an 8-slot B-frag register ring:
//    frag(i, Uk+1) = frag(i-2, Uk) -> per Uk: 2 fresh B reads + 1 A read,
//    8 MFMAs. 8 phases of 256 u; B band per phase: z in [1544-tB+256ph, +768).
//  bx in [256,768): pos via MFMA (in-register sins, hi/lo W).
//  bx in [768,784): s-branch MLP.
// ---------------------------------------------------------------------------
__global__ __launch_bounds__(256) void mega_k(const unsigned short* __restrict__ tsh_b,
                                              const unsigned short* __restrict__ BFrep,
                                              float* __restrict__ expT,
                                              const float* __restrict__ w_pos,
                                              const float* __restrict__ b_pos,
                                              float* __restrict__ pos,
                                              const float* __restrict__ shape,
                                              const float* __restrict__ w_layers,
                                              const float* __restrict__ b_layers,
                                              float* __restrict__ s64) {
  __shared__ __align__(16) unsigned char smem[21248];
  int bx = blockIdx.x;
  int tid = threadIdx.x;
  if (bx < 256) {
    int j = bx >> 2, tB = (bx & 3) << 9;
    int l = tid & 63, w = tid >> 6;
    int p16 = l & 15, g = l >> 4;
    int hb = p16 >> 3, srep = p16 & 7;
    int TBw = tB + (w << 7);

    float4v acc[8];
#pragma unroll
    for (int i = 0; i < 8; ++i) acc[i] = (float4v){0.f, 0.f, 0.f, 0.f};
    short8v W[8];

    int bofB = 8192 + srep * 1552 + 1008 - (w << 8) - (hb << 4) + (g << 4);
#define LDB_E(i, q) (*(const short8v*)(smem + bofB - 32 * (i) + 64 * (q)))

    for (int ph = 0; ph < 8; ++ph) {
      __syncthreads();
      // stage A: 16 p x 256 u, XOR swizzled
#pragma unroll
      for (int it = 0; it < 2; ++it) {
        int c = tid + (it << 8);
        int pp = c >> 5, m = c & 31;
        short8v v = *(const short8v*)(tsh_b + pp * 2048 + (ph << 8) + (m << 3));
        int dst = ((pp << 9) + (m << 4)) ^ ((pp & 7) << 4);
        *(short8v*)(smem + dst) = v;
      }
      // stage B: 8 replicas x 768 elems band
      int base_z = 1544 - tB + (ph << 8);
#pragma unroll
      for (int it = 0; it < 3; ++it) {
        int c = tid + (it << 8);
        int sc = c / 96;
        int m = c - sc * 96;
        short8v v = *(const short8v*)(BFrep + ((size_t)(j * 8 + sc)) * 4104 + base_z + (m << 3));
        *(short8v*)(smem + 8192 + sc * 1552 + (m << 4)) = v;
      }
      __syncthreads();
      if (ph == 0) {
#pragma unroll
        for (int i = 2; i < 8; ++i) W[i] = LDB_E(i, 0);
      }
#pragma unroll
      for (int q = 0; q < 8; ++q) {
        W[0] = LDB_E(0, q);
        W[1] = LDB_E(1, q);
        int ao = ((p16 << 9) + (q << 6) + (g << 4)) ^ ((p16 & 7) << 4);
        short8v a = *(const short8v*)(smem + ao);
#pragma unroll
        for (int i = 0; i < 8; ++i)
          acc[i] = __builtin_amdgcn_mfma_f32_16x16x32_bf16(a, W[i], acc[i], 0, 0, 0);
        W[7] = W[5]; W[6] = W[4]; W[5] = W[3]; W[4] = W[2]; W[3] = W[1]; W[2] = W[0];
      }
    }
#undef LDB_E
#pragma unroll
    for (int i = 0; i < 8; ++i) {
      int t = TBw + (i << 4) + p16;
#pragma unroll
      for (int rr = 0; rr < 4; ++rr) {
        int prow = (g << 2) + rr;
        expT[(size_t)(prow * 64 + j) * TL + t] = acc[i][rr];
      }
    }
  } else if (bx < 768) {
    int l = tid & 63, w = tid >> 6;
    int p16 = l & 15, g = l >> 4;
    int T0 = (bx - 256) * 64 + w * 16;

    short8v bhi0[8], blo0[8], bhi1[8], blo1[8];
#pragma unroll
    for (int kc = 0; kc < 8; ++kc) {
#pragma unroll
      for (int ct = 0; ct < 2; ++ct) {
        const float* wrow = w_pos + (ct * 16 + p16) * 256 + kc * 32 + g * 8;
        float4v w0 = *(const float4v*)(wrow);
        float4v w1 = *(const float4v*)(wrow + 4);
        short8v hv, lv;
#pragma unroll
        for (int i = 0; i < 8; ++i) {
          float vv = (i < 4) ? w0[i] : w1[i - 4];
          unsigned short h = bf16_rne(vv);
          float hf = __uint_as_float(((unsigned)h) << 16);
          hv[i] = (short)h;
          lv[i] = (short)bf16_rne(vv - hf);
        }
        if (ct == 0) { bhi0[kc] = hv; blo0[kc] = lv; }
        else         { bhi1[kc] = hv; blo1[kc] = lv; }
      }
    }

    float ttv = (float)(T0 + p16) * (32768.0f / 32767.0f);
    float4v acc0 = {0.f, 0.f, 0.f, 0.f};
    float4v acc1 = {0.f, 0.f, 0.f, 0.f};
#pragma unroll
    for (int kc = 0; kc < 8; ++kc) {
      short8v ahi, alo;
#pragma unroll
      for (int i = 0; i < 8; ++i) {
        int f = kc * 32 + g * 8 + i;
        float fr = 1e-5f + (float)f * ((0.5f - 1e-5f) / 255.0f);
        float rev = ttv * (0.5f * fr);
        float sv = __builtin_amdgcn_sinf(__builtin_amdgcn_fractf(rev));
        unsigned short h = bf16_rne(sv);
        float hf = __uint_as_float(((unsigned)h) << 16);
        ahi[i] = (short)h;
        alo[i] = (short)bf16_rne(sv - hf);
      }
      acc0 = __builtin_amdgcn_mfma_f32_16x16x32_bf16(ahi, bhi0[kc], acc0, 0, 0, 0);
      acc1 = __builtin_amdgcn_mfma_f32_16x16x32_bf16(ahi, bhi1[kc], acc1, 0, 0, 0);
      acc0 = __builtin_amdgcn_mfma_f32_16x16x32_bf16(ahi, blo0[kc], acc0, 0, 0, 0);
      acc1 = __builtin_amdgcn_mfma_f32_16x16x32_bf16(ahi, blo1[kc], acc1, 0, 0, 0);
      acc0 = __builtin_amdgcn_mfma_f32_16x16x32_bf16(alo, bhi0[kc], acc0, 0, 0, 0);
      acc1 = __builtin_amdgcn_mfma_f32_16x16x32_bf16(alo, bhi1[kc], acc1, 0, 0, 0);
    }
    float bp0 = b_pos[p16], bp1 = b_pos[16 + p16];
    float4v o0, o1;
#pragma unroll
    for (int rr = 0; rr < 4; ++rr) {
      o0[rr] = acc0[rr] + bp0;
      o1[rr] = acc1[rr] + bp1;
    }
    int Tr = T0 + g * 4;
    *(float4v*)(pos + (size_t)p16 * 32768 + Tr) = o0;
    *(float4v*)(pos + (size_t)(16 + p16) * 32768 + Tr) = o1;
  } else {
    float(*sA)[33] = (float(*)[33])(smem);
    float(*sB)[33] = (float(*)[33])(smem + 8448);
    float(*W)[33] = (float(*)[33])(smem + 16896);
    float* bb = (float*)(smem + 21120);
    int p = bx - 768;
    for (int idx = tid; idx < 2048; idx += 256) {
      int c = idx >> 6, f = idx & 63;
      sA[f][c] = shape[p * 2048 + idx];
    }
    int c = tid & 31, fg = tid >> 5;
    for (int ll = 0; ll < 4; ++ll) {
      for (int idx = tid; idx < 1024; idx += 256) W[idx >> 5][idx & 31] = w_layers[ll * 1024 + idx];
      if (tid < 32) bb[tid] = b_layers[ll * 32 + tid];
      __syncthreads();
      float(*cur)[33] = (ll & 1) ? sB : sA;
      float(*nxt)[33] = (ll & 1) ? sA : sB;
#pragma unroll
      for (int i = 0; i < 8; ++i) {
        int f = fg * 8 + i;
        float acc = cur[f][c] + bb[c];
#pragma unroll
        for (int k = 0; k < 32; ++k) acc = fmaf(fmaxf(cur[f][k], 0.f), W[c][k], acc);
        nxt[f][c] = acc;
      }
      __syncthreads();
    }
    for (int idx = tid; idx < 2048; idx += 256) {
      int cc = idx >> 6, f = idx & 63;
      s64[p * 2048 + idx] = fmaxf(sA[f][cc], 0.f);
    }
  }
}

// ---------------------------------------------------------------------------
// env fused with mask: msk[p,j,t] = kerC[p][t+2046-j] - kerC[p][t]
// ---------------------------------------------------------------------------
__global__ __launch_bounds__(256) void env2_k(const float* __restrict__ energy,
                                              const float* __restrict__ props,
                                              const float* __restrict__ expT,
                                              const float* __restrict__ kerC,
                                              float* __restrict__ env) {
  int p = blockIdx.x >> 5, tile = blockIdx.x & 31;
  int tl = threadIdx.x & 63;
  int cg = threadIdx.x >> 6;
  int tC = tile * 64;
  int t = tC + tl;
  __shared__ float E[32][64];
  __shared__ float K[32];
  __shared__ float kcl[2112];
  for (int i = threadIdx.x; i < 2048; i += 256) E[i >> 6][i & 63] = energy[p * 2048 + i];
  const float* crow = kerC + p * 4096;
  for (int i = threadIdx.x; i < 2110; i += 256) kcl[i] = crow[tC + i];
  if (threadIdx.x < 32) {
    float mass = props[(p * 32 + threadIdx.x) * 2];
    float fric = props[(p * 32 + threadIdx.x) * 2 + 1];
    K[threadIdx.x] = fric / (2.0f * mass);
  }
  __syncthreads();
  float acc[8];
  float kk[8];
#pragma unroll
  for (int i = 0; i < 8; ++i) acc[i] = 0.f;
#pragma unroll
  for (int i = 0; i < 8; ++i) kk[i] = K[cg * 8 + i];
  float Ct = kcl[tl];
  const float* xrow = expT + (size_t)p * 64 * TL + t;
  for (int jj = 0; jj < 64; ++jj) {
    float x = xrow[jj * TL];
    float mv = kcl[tl + 2046 - jj] - Ct;
#pragma unroll
    for (int cc = 0; cc < 8; ++cc)
      acc[cc] = fmaf(E[cg * 8 + cc][jj] * mv, __expf(-kk[cc] * x), acc[cc]);
  }
#pragma unroll
  for (int cc = 0; cc < 8; ++cc)
    env[(size_t)(p * 32 + cg * 8 + cc) * TL + t] = acc[cc];
}

// ---------------------------------------------------------------------------
// Final (unchanged)
// ---------------------------------------------------------------------------
__global__ __launch_bounds__(256) void final_k(const float* __restrict__ pos,
                                               const float* __restrict__ s64,
                                               const float* __restrict__ env,
                                               float* __restrict__ out) {
  int gid = blockIdx.x * 256 + threadIdx.x;
  int p = gid >> 15, T = gid & 32767;
  float ft = (float)T + 0.5f;
  float ce = fminf(fmaxf(ft * 0.0625f - 0.5f, 0.f), 2047.f);
  int ie = (int)ce;
  int ie1 = min(ie + 1, 2047);
  float we = ce - (float)ie;
  float cs = fminf(fmaxf(ft * (1.0f / 512.0f) - 0.5f, 0.f), 63.f);
  int is0 = (int)cs;
  int is1 = min(is0 + 1, 63);
  float ws = cs - (float)is0;
  const float* erow = env + (size_t)p * 32 * TL;
  const float* srow = s64 + p * 32 * 64;
  float acc = 0.f;
  for (int c = 0; c < 32; ++c) {
    float pv = pos[(size_t)c * 32768 + T];
    float ev = fmaxf(erow[c * TL + ie] * (1.f - we) + erow[c * TL + ie1] * we, 0.f);
    float sv = srow[c * 64 + is0] * (1.f - ws) + srow[c * 64 + is1] * ws;
    acc += pv * sv * ev;
  }
  out[gid] = acc;
}

extern "C" void kernel_launch(void* const* d_in, const int* in_sizes, int n_in,
                              void* d_out, int out_size, void* d_ws, size_t ws_size,
                              hipStream_t stream) {
  const float* time_in  = (const float*)d_in[0];
  const float* shifts   = (const float*)d_in[1];
  const float* energy   = (const float*)d_in[2];
  const float* shape    = (const float*)d_in[3];
  const float* props    = (const float*)d_in[4];
  const float* w_pos    = (const float*)d_in[5];
  const float* b_pos    = (const float*)d_in[6];
  const float* w_layers = (const float*)d_in[7];
  const float* b_layers = (const float*)d_in[8];

  float* ws = (float*)d_ws;
  float* kerC = ws;                                        // 65536 f
  unsigned short* BFrep = (unsigned short*)(ws + 65536);   // 80*8*4104 u16 = 1313280 f
  unsigned short* tsh_b = (unsigned short*)(ws + 1378816); // 32768 u16 = 16384 f
  float* expT = ws + 1395200;                              // 2097152 f
  float* env  = ws + 3492352;                              // 1048576 f
  float* pos  = ws + 4540928;                              // 1048576 f
  float* s64  = ws + 5589504;                              // 32768 f
  float* out  = (float*)d_out;

  hipLaunchKernelGGL(build_kernels_k, dim3(80), dim3(256), 0, stream, shifts, kerC, BFrep);
  hipLaunchKernelGGL(tsh_mfma_k, dim3(16), dim3(256), 0, stream, time_in, BFrep, tsh_b);
  hipLaunchKernelGGL(mega_k, dim3(784), dim3(256), 0, stream, tsh_b, BFrep, expT,
                     w_pos, b_pos, pos, shape, w_layers, b_layers, s64);
  hipLaunchKernelGGL(env2_k, dim3(512), dim3(256), 0, stream, energy, props, expT, kerC, env);
  hipLaunchKernelGGL(final_k, dim3(2048), dim3(256), 0, stream, pos, s64, env, out);
}

// Round 6
// 102.892 us; speedup vs baseline: 1.3195x; 1.3195x over previous
//
#include <hip/hip_runtime.h>
#include <math.h>

#define TL 2048
#define PI_D 3.14159265358979323846

typedef __attribute__((ext_vector_type(8))) short short8v;
typedef __attribute__((ext_vector_type(4))) float float4v;

#define REPLEN 392
#define REPB (REPLEN * 2)   // 784 bytes per replica row
#define OFF_B 8192          // A-tile occupies smem[0..8192)

__device__ __forceinline__ unsigned short bf16_rne(float f) {
  unsigned u = __float_as_uint(f);
  return (unsigned short)((u + 0x7FFFu + ((u >> 16) & 1u)) >> 16);
}

// tap value k[d] for shift param (beta, wv); d = idx - 2047
__device__ __forceinline__ float tap_val(int idx, double beta, double wv) {
  int d = idx - 2047;
  double x = PI_D * (double)d / 6144.0 - beta;
  if (fabs(x) < 1e-9) return 1.0f;
  double c = wv * (cos(x) / sin(x));
  if (d & 1) c = -c;
  return (float)c;
}

// ---------------------------------------------------------------------------
// K1 (208 blocks):
//  b in [0,64):   frame kernel b -> BFrep bf16 shift-replicas (G-layout).
//  b in [64,80):  event kernel (b-64) -> kerC exclusive tap prefix (mask id).
//  b in [80,208): shift_time for p=(b-80)>>3, tile=(b-80)&7, taps computed
//                 INLINE (no dependency on other blocks): tsh bf16 out.
// k[d] = -(sin(2*pi*r)/N)*(-1)^d * cot(pi*d/N - beta), N=6144,
// beta=pi*s/3073, r=frac(3072 s/3073), s=shift*2048/3; d->0 limit = 1.
// ---------------------------------------------------------------------------
__global__ __launch_bounds__(256) void build_shift_k(const float* __restrict__ shifts,
                                                     const float* __restrict__ time_in,
                                                     float* __restrict__ kerC,
                                                     unsigned short* __restrict__ BFrep,
                                                     unsigned short* __restrict__ tsh_b) {
  __shared__ __align__(16) unsigned char sm1[17408];
  __shared__ float wsum[4];
  int b = blockIdx.x;
  int tid = threadIdx.x;
  if (b < 80) {
    float* kf = (float*)sm1;  // 4104 floats
    double s;
    if (b < 64) s = (double)b * (1.0 / 63.0) * (2048.0 / 3.0);
    else        s = (double)shifts[b - 64] * (2048.0 / 3.0);
    double beta = PI_D * s / 3073.0;
    double y = 3072.0 * s / 3073.0;
    double r = y - rint(y);
    double wv = -sin(2.0 * PI_D * r) / 6144.0;
    for (int idx = tid; idx < 4104; idx += 256)
      kf[idx] = (idx < 4095) ? tap_val(idx, beta, wv) : 0.0f;
    __syncthreads();
    if (b < 64) {
      for (int c = tid; c < 4096; c += 256) {
        int sr = c >> 9;
        int m = c & 511;
        int A = 4095 - 8 * m + sr;
        unsigned short out[8];
#pragma unroll
        for (int rr = 0; rr < 8; ++rr) out[rr] = bf16_rne(kf[A - rr]);
        *(short8v*)(BFrep + ((size_t)(b * 8 + sr)) * 4104 + 8 * m) = *(short8v*)out;
      }
    } else {
      float s0 = 0.f;
      int base = tid * 16;
#pragma unroll
      for (int i = 0; i < 16; ++i) s0 += kf[base + i];
      int lane = tid & 63;
      float v = s0;
#pragma unroll
      for (int d = 1; d < 64; d <<= 1) {
        float o = __shfl_up(v, (unsigned)d, 64);
        if (lane >= d) v += o;
      }
      if (lane == 63) wsum[tid >> 6] = v;
      __syncthreads();
      float woff = 0.f;
      for (int k = 0; k < (tid >> 6); ++k) woff += wsum[k];
      float run = v + woff - s0;
      float* crow = kerC + (b - 64) * 4096;
#pragma unroll
      for (int i = 0; i < 16; ++i) {
        crow[base + i] = run;
        run += kf[base + i];
      }
    }
  } else {
    // shift_time with inline taps
    int pb = b - 80;
    int p = pb >> 3, tile = pb & 7;
    float* a = (float*)sm1;            // 2048 floats
    float* kw = (float*)(sm1 + 8192);  // 2304 floats
    int t0 = tile * 256;
    double s = (double)shifts[p] * (2048.0 / 3.0);
    double beta = PI_D * s / 3073.0;
    double y = 3072.0 * s / 3073.0;
    double r = y - rint(y);
    double wv = -sin(2.0 * PI_D * r) / 6144.0;
    for (int i = tid; i < 2048; i += 256) a[i] = time_in[p * 2048 + i];
    for (int i = tid; i < 2303; i += 256) kw[i] = tap_val(t0 + i, beta, wv);
    __syncthreads();
    float acc = 0.f;
    int base = tid + 2047;
#pragma unroll 8
    for (int u = 0; u < 2048; ++u) acc = fmaf(a[u], kw[base - u], acc);
    tsh_b[p * 2048 + t0 + tid] = bf16_rne(acc);
  }
}

// ---------------------------------------------------------------------------
// K2 (1552 blocks, 4 blocks/CU):
//  bx in [0,1024): expT via MFMA with K-split 4-slot B-ring.
//    j = bx>>4, tB = (bx&15)*128. Wave w: h=w>>1 (t-half, 64 t = 4 col-tiles),
//    kp=w&1 (u-chunks 4kp..4kp+3 of each 256-u phase). Ring:
//    frag(ct,kc+1)=frag(ct-2,kc) -> per phase 10 B + 4 A reads, 16 MFMA.
//    Epilogue: kp=1 waves dump acc to LDS, kp=0 waves add + store.
//  bx in [1024,1536): pos via MFMA (in-register sins, lazy hi/lo W loads).
//  bx in [1536,1552): s-branch MLP.
// ---------------------------------------------------------------------------
__global__ __launch_bounds__(256, 4) void fused_k(const unsigned short* __restrict__ tsh_b,
                                                  const unsigned short* __restrict__ BFrep,
                                                  float* __restrict__ expT,
                                                  const float* __restrict__ w_pos,
                                                  const float* __restrict__ b_pos,
                                                  float* __restrict__ pos,
                                                  const float* __restrict__ shape,
                                                  const float* __restrict__ w_layers,
                                                  const float* __restrict__ b_layers,
                                                  float* __restrict__ s64) {
  __shared__ __align__(16) unsigned char smem[21248];
  int bx = blockIdx.x;
  int tid = threadIdx.x;
  if (bx < 1024) {
    int j = bx >> 4;
    int tB = (bx & 15) << 7;
    int l = tid & 63, w = tid >> 6;
    int p16 = l & 15, g = l >> 4;
    int srep = l & 7, hb = (l >> 3) & 1;
    int h = w >> 1, kp = w & 1;
    int kc0 = kp << 2;

    float4v acc[4];
#pragma unroll
    for (int i = 0; i < 4; ++i) acc[i] = (float4v){0.f, 0.f, 0.f, 0.f};
    // frag(ct,kc) byte addr = bB2 - 32*ct + 64*kc
    int bB2 = OFF_B + srep * REPB + 256 - (hb << 4) + (g << 4) - (h << 7);
    const unsigned short* grow = BFrep + (size_t)j * 8 * 4104;

    for (int ph = 0; ph < 8; ++ph) {
      int ub = ph << 8;
      int Q8 = 1912 - tB + ub;
      __syncthreads();
      // stage A: 16 p x 256 u bf16, XOR swizzled
#pragma unroll
      for (int it = 0; it < 2; ++it) {
        int c = tid + (it << 8);
        int pp = c >> 5, m = c & 31;
        short8v v = *(const short8v*)(tsh_b + pp * 2048 + ub + (m << 3));
        int dst = ((pp << 9) + (m << 4)) ^ ((pp & 7) << 4);
        *(short8v*)(smem + dst) = v;
      }
      // stage B: 8 replicas x 384-elem band
      for (int c = tid; c < 384; c += 256) {
        int sr = c / 48;
        int m = c - sr * 48;
        short8v v = *(const short8v*)(grow + sr * 4104 + 8 + Q8 + (m << 3));
        *(short8v*)(smem + OFF_B + sr * REPB + (m << 4)) = v;
      }
      __syncthreads();
      int fb = bB2 + (kc0 << 6);
      short8v W0 = *(const short8v*)(smem + fb);
      short8v W1 = *(const short8v*)(smem + fb - 32);
      short8v W2 = *(const short8v*)(smem + fb - 64);
      short8v W3 = *(const short8v*)(smem + fb - 96);
#pragma unroll
      for (int qq = 0; qq < 4; ++qq) {
        int kc = kc0 + qq;
        if (qq > 0) {
          short8v t2 = W0, t3 = W1;
          W0 = *(const short8v*)(smem + fb + (qq << 6));
          W1 = *(const short8v*)(smem + fb + (qq << 6) - 32);
          W2 = t2;
          W3 = t3;
        }
        int ao = ((p16 << 9) + (kc << 6) + (g << 4)) ^ ((p16 & 7) << 4);
        short8v a = *(const short8v*)(smem + ao);
        acc[0] = __builtin_amdgcn_mfma_f32_16x16x32_bf16(a, W0, acc[0], 0, 0, 0);
        acc[1] = __builtin_amdgcn_mfma_f32_16x16x32_bf16(a, W1, acc[1], 0, 0, 0);
        acc[2] = __builtin_amdgcn_mfma_f32_16x16x32_bf16(a, W2, acc[2], 0, 0, 0);
        acc[3] = __builtin_amdgcn_mfma_f32_16x16x32_bf16(a, W3, acc[3], 0, 0, 0);
      }
    }
    // cross-wave K reduction (kp=1 -> LDS, kp=0 adds and stores)
    __syncthreads();
    if (kp == 1) {
#pragma unroll
      for (int ct = 0; ct < 4; ++ct)
        *(float4v*)(smem + ((((h << 2) + ct) << 6) + l) * 16) = acc[ct];
    }
    __syncthreads();
    if (kp == 0) {
#pragma unroll
      for (int ct = 0; ct < 4; ++ct) {
        float4v o = *(const float4v*)(smem + ((((h << 2) + ct) << 6) + l) * 16);
#pragma unroll
        for (int rr = 0; rr < 4; ++rr) acc[ct][rr] += o[rr];
      }
      int tbase = tB + (h << 6) + p16;
#pragma unroll
      for (int ct = 0; ct < 4; ++ct) {
#pragma unroll
        for (int rr = 0; rr < 4; ++rr) {
          int prow = (g << 2) + rr;
          expT[(size_t)(prow * 64 + j) * TL + tbase + (ct << 4)] = acc[ct][rr];
        }
      }
    }
  } else if (bx < 1536) {
    int l = tid & 63, w = tid >> 6;
    int p16 = l & 15, g = l >> 4;
    int T0 = (bx - 1024) * 64 + w * 16;

    float ttv = (float)(T0 + p16) * (32768.0f / 32767.0f);
    float4v acc0 = {0.f, 0.f, 0.f, 0.f};
    float4v acc1 = {0.f, 0.f, 0.f, 0.f};
#pragma unroll
    for (int kc = 0; kc < 8; ++kc) {
      // lazy W loads (hi/lo), 2 col-tiles
      short8v bh0, bl0, bh1, bl1;
#pragma unroll
      for (int ct = 0; ct < 2; ++ct) {
        const float* wrow = w_pos + (ct * 16 + p16) * 256 + kc * 32 + g * 8;
        float4v w0 = *(const float4v*)(wrow);
        float4v w1 = *(const float4v*)(wrow + 4);
        short8v hv, lv;
#pragma unroll
        for (int i = 0; i < 8; ++i) {
          float vv = (i < 4) ? w0[i] : w1[i - 4];
          unsigned short hbit = bf16_rne(vv);
          float hf = __uint_as_float(((unsigned)hbit) << 16);
          hv[i] = (short)hbit;
          lv[i] = (short)bf16_rne(vv - hf);
        }
        if (ct == 0) { bh0 = hv; bl0 = lv; }
        else         { bh1 = hv; bl1 = lv; }
      }
      short8v ahi, alo;
#pragma unroll
      for (int i = 0; i < 8; ++i) {
        int f = kc * 32 + g * 8 + i;
        float fr = 1e-5f + (float)f * ((0.5f - 1e-5f) / 255.0f);
        float rev = ttv * (0.5f * fr);
        float sv = __builtin_amdgcn_sinf(__builtin_amdgcn_fractf(rev));
        unsigned short hbit = bf16_rne(sv);
        float hf = __uint_as_float(((unsigned)hbit) << 16);
        ahi[i] = (short)hbit;
        alo[i] = (short)bf16_rne(sv - hf);
      }
      acc0 = __builtin_amdgcn_mfma_f32_16x16x32_bf16(ahi, bh0, acc0, 0, 0, 0);
      acc1 = __builtin_amdgcn_mfma_f32_16x16x32_bf16(ahi, bh1, acc1, 0, 0, 0);
      acc0 = __builtin_amdgcn_mfma_f32_16x16x32_bf16(ahi, bl0, acc0, 0, 0, 0);
      acc1 = __builtin_amdgcn_mfma_f32_16x16x32_bf16(ahi, bl1, acc1, 0, 0, 0);
      acc0 = __builtin_amdgcn_mfma_f32_16x16x32_bf16(alo, bh0, acc0, 0, 0, 0);
      acc1 = __builtin_amdgcn_mfma_f32_16x16x32_bf16(alo, bh1, acc1, 0, 0, 0);
    }
    float bp0 = b_pos[p16], bp1 = b_pos[16 + p16];
    float4v o0, o1;
#pragma unroll
    for (int rr = 0; rr < 4; ++rr) {
      o0[rr] = acc0[rr] + bp0;
      o1[rr] = acc1[rr] + bp1;
    }
    int Tr = T0 + g * 4;
    *(float4v*)(pos + (size_t)p16 * 32768 + Tr) = o0;
    *(float4v*)(pos + (size_t)(16 + p16) * 32768 + Tr) = o1;
  } else {
    float(*sA)[33] = (float(*)[33])(smem);
    float(*sB)[33] = (float(*)[33])(smem + 8448);
    float(*W)[33] = (float(*)[33])(smem + 16896);
    float* bb = (float*)(smem + 21120);
    int p = bx - 1536;
    for (int idx = tid; idx < 2048; idx += 256) {
      int c = idx >> 6, f = idx & 63;
      sA[f][c] = shape[p * 2048 + idx];
    }
    int c = tid & 31, fg = tid >> 5;
    for (int ll = 0; ll < 4; ++ll) {
      for (int idx = tid; idx < 1024; idx += 256) W[idx >> 5][idx & 31] = w_layers[ll * 1024 + idx];
      if (tid < 32) bb[tid] = b_layers[ll * 32 + tid];
      __syncthreads();
      float(*cur)[33] = (ll & 1) ? sB : sA;
      float(*nxt)[33] = (ll & 1) ? sA : sB;
#pragma unroll
      for (int i = 0; i < 8; ++i) {
        int f = fg * 8 + i;
        float acc = cur[f][c] + bb[c];
#pragma unroll
        for (int k = 0; k < 32; ++k) acc = fmaf(fmaxf(cur[f][k], 0.f), W[c][k], acc);
        nxt[f][c] = acc;
      }
      __syncthreads();
    }
    for (int idx = tid; idx < 2048; idx += 256) {
      int cc = idx >> 6, f = idx & 63;
      s64[p * 2048 + idx] = fmaxf(sA[f][cc], 0.f);
    }
  }
}

// ---------------------------------------------------------------------------
// env fused with mask: msk[p,j,t] = kerC[p][t+2046-j] - kerC[p][t]
// ---------------------------------------------------------------------------
__global__ __launch_bounds__(256) void env2_k(const float* __restrict__ energy,
                                              const float* __restrict__ props,
                                              const float* __restrict__ expT,
                                              const float* __restrict__ kerC,
                                              float* __restrict__ env) {
  int p = blockIdx.x >> 5, tile = blockIdx.x & 31;
  int tl = threadIdx.x & 63;
  int cg = threadIdx.x >> 6;
  int tC = tile * 64;
  int t = tC + tl;
  __shared__ float E[32][64];
  __shared__ float K[32];
  __shared__ float kcl[2112];
  for (int i = threadIdx.x; i < 2048; i += 256) E[i >> 6][i & 63] = energy[p * 2048 + i];
  const float* crow = kerC + p * 4096;
  for (int i = threadIdx.x; i < 2110; i += 256) kcl[i] = crow[tC + i];
  if (threadIdx.x < 32) {
    float mass = props[(p * 32 + threadIdx.x) * 2];
    float fric = props[(p * 32 + threadIdx.x) * 2 + 1];
    K[threadIdx.x] = fric / (2.0f * mass);
  }
  __syncthreads();
  float acc[8];
  float kk[8];
#pragma unroll
  for (int i = 0; i < 8; ++i) acc[i] = 0.f;
#pragma unroll
  for (int i = 0; i < 8; ++i) kk[i] = K[cg * 8 + i];
  float Ct = kcl[tl];
  const float* xrow = expT + (size_t)p * 64 * TL + t;
  for (int jj = 0; jj < 64; ++jj) {
    float x = xrow[jj * TL];
    float mv = kcl[tl + 2046 - jj] - Ct;
#pragma unroll
    for (int cc = 0; cc < 8; ++cc)
      acc[cc] = fmaf(E[cg * 8 + cc][jj] * mv, __expf(-kk[cc] * x), acc[cc]);
  }
#pragma unroll
  for (int cc = 0; cc < 8; ++cc)
    env[(size_t)(p * 32 + cg * 8 + cc) * TL + t] = acc[cc];
}

// ---------------------------------------------------------------------------
// Final (unchanged)
// ---------------------------------------------------------------------------
__global__ __launch_bounds__(256) void final_k(const float* __restrict__ pos,
                                               const float* __restrict__ s64,
                                               const float* __restrict__ env,
                                               float* __restrict__ out) {
  int gid = blockIdx.x * 256 + threadIdx.x;
  int p = gid >> 15, T = gid & 32767;
  float ft = (float)T + 0.5f;
  float ce = fminf(fmaxf(ft * 0.0625f - 0.5f, 0.f), 2047.f);
  int ie = (int)ce;
  int ie1 = min(ie + 1, 2047);
  float we = ce - (float)ie;
  float cs = fminf(fmaxf(ft * (1.0f / 512.0f) - 0.5f, 0.f), 63.f);
  int is0 = (int)cs;
  int is1 = min(is0 + 1, 63);
  float ws = cs - (float)is0;
  const float* erow = env + (size_t)p * 32 * TL;
  const float* srow = s64 + p * 32 * 64;
  float acc = 0.f;
  for (int c = 0; c < 32; ++c) {
    float pv = pos[(size_t)c * 32768 + T];
    float ev = fmaxf(erow[c * TL + ie] * (1.f - we) + erow[c * TL + ie1] * we, 0.f);
    float sv = srow[c * 64 + is0] * (1.f - ws) + srow[c * 64 + is1] * ws;
    acc += pv * sv * ev;
  }
  out[gid] = acc;
}

extern "C" void kernel_launch(void* const* d_in, const int* in_sizes, int n_in,
                              void* d_out, int out_size, void* d_ws, size_t ws_size,
                              hipStream_t stream) {
  const float* time_in  = (const float*)d_in[0];
  const float* shifts   = (const float*)d_in[1];
  const float* energy   = (const float*)d_in[2];
  const float* shape    = (const float*)d_in[3];
  const float* props    = (const float*)d_in[4];
  const float* w_pos    = (const float*)d_in[5];
  const float* b_pos    = (const float*)d_in[6];
  const float* w_layers = (const float*)d_in[7];
  const float* b_layers = (const float*)d_in[8];

  float* ws = (float*)d_ws;
  float* kerC = ws;                                        // 65536 f
  unsigned short* BFrep = (unsigned short*)(ws + 65536);   // 64*8*4104 u16 = 1050624 f
  unsigned short* tsh_b = (unsigned short*)(ws + 1116160); // 32768 u16 = 16384 f
  float* expT = ws + 1132544;                              // 2097152 f
  float* env  = ws + 3229696;                              // 1048576 f
  float* pos  = ws + 4278272;                              // 1048576 f
  float* s64  = ws + 5326848;                              // 32768 f
  float* out  = (float*)d_out;

  hipLaunchKernelGGL(build_shift_k, dim3(208), dim3(256), 0, stream,
                     shifts, time_in, kerC, BFrep, tsh_b);
  hipLaunchKernelGGL(fused_k, dim3(1552), dim3(256), 0, stream, tsh_b, BFrep, expT,
                     w_pos, b_pos, pos, shape, w_layers, b_layers, s64);
  hipLaunchKernelGGL(env2_k, dim3(512), dim3(256), 0, stream, energy, props, expT, kerC, env);
  hipLaunchKernelGGL(final_k, dim3(2048), dim3(256), 0, stream, pos, s64, env, out);
}